// Round 1
// baseline (128.548 us; speedup 1.0000x reference)
//
#include <hip/hip_runtime.h>

// Gemma3n AltUp fused: predict + correct in one kernel.
// Shapes: hidden_states [4, T, H], activated [T, H], w_norm [H],
//         W_router [4, H], W_pred [16, 4], W_corr [4, 4], out [4, T, H]
// T = B*S = 8192, H = 2048. All fp32. Memory-bound (~604 MB HBM traffic).

constexpr int H = 2048;
constexpr float EPS = 1e-6f;

__global__ __launch_bounds__(256) void altup_fused(
    const float* __restrict__ hs,       // [4, T, H]
    const float* __restrict__ act,      // [T, H]
    const float* __restrict__ w_norm,   // [H]
    const float* __restrict__ W_router, // [4, H]
    const float* __restrict__ W_pred,   // [16, 4]
    const float* __restrict__ W_corr,   // [4, 4]
    float* __restrict__ out,            // [4, T, H]
    long long T)
{
    const long long t = blockIdx.x;
    const int tid = threadIdx.x;
    const long long row = t * (long long)H;
    const long long plane = T * (long long)H;

    __shared__ float s_x0[H];      // hidden_states[0] row (active)
    __shared__ float s_xc[H];      // activated row
    __shared__ float s_red[4][10]; // per-wave partials

    // ---- pass 1: sum-of-squares + router dots for both rows ----
    // p[0]=ssq(active), p[1..4]=dot(active*w_norm, W_router[i])
    // p[5]=ssq(activated), p[6..9]=dot(activated*w_norm, W_router[i])
    float p[10];
#pragma unroll
    for (int i = 0; i < 10; ++i) p[i] = 0.f;

#pragma unroll
    for (int c = 0; c < 2; ++c) {
        const int h = c * 1024 + tid * 4;
        const float4 xa4 = *reinterpret_cast<const float4*>(hs + row + h);
        const float4 xc4 = *reinterpret_cast<const float4*>(act + row + h);
        const float4 wn4 = *reinterpret_cast<const float4*>(w_norm + h);
        *reinterpret_cast<float4*>(s_x0 + h) = xa4;
        *reinterpret_cast<float4*>(s_xc + h) = xc4;
        const float* a = &xa4.x;
        const float* cc = &xc4.x;
        const float* w = &wn4.x;
#pragma unroll
        for (int e = 0; e < 4; ++e) {
            p[0] += a[e] * a[e];
            p[5] += cc[e] * cc[e];
        }
#pragma unroll
        for (int i = 0; i < 4; ++i) {
            const float4 wr4 = *reinterpret_cast<const float4*>(W_router + i * H + h);
            const float* r = &wr4.x;
#pragma unroll
            for (int e = 0; e < 4; ++e) {
                p[1 + i] += a[e] * w[e] * r[e];
                p[6 + i] += cc[e] * w[e] * r[e];
            }
        }
    }

    // wave-64 butterfly reduce
#pragma unroll
    for (int m = 1; m < 64; m <<= 1) {
#pragma unroll
        for (int i = 0; i < 10; ++i) p[i] += __shfl_xor(p[i], m, 64);
    }
    const int wave = tid >> 6;
    const int lane = tid & 63;
    if (lane == 0) {
#pragma unroll
        for (int i = 0; i < 10; ++i) s_red[wave][i] = p[i];
    }
    __syncthreads();

    float tot[10];
#pragma unroll
    for (int i = 0; i < 10; ++i)
        tot[i] = s_red[0][i] + s_red[1][i] + s_red[2][i] + s_red[3][i];

    // ---- tiny coefficient math (redundant per thread; scalar broadcasts) ----
    const float ris = 1.0f / (float)H;                 // ROUTER_INPUT_SCALE = 1/H
    const float inv_a = rsqrtf(tot[0] * ris + EPS) * ris; // rsqrt(var+eps) * 1/H
    const float inv_c = rsqrtf(tot[5] * ris + EPS) * ris;
    float mods[4], modsc[4];
#pragma unroll
    for (int i = 0; i < 4; ++i) {
        mods[i]  = tanhf(tot[1 + i] * inv_a);
        modsc[i] = tanhf(tot[6 + i] * inv_c);
    }
    // coefs = mods @ W_pred.T  -> [16] -> reshape [4][4] -> swapaxes:
    // coefT[k][j] = coefs_flat[j*4+k] = sum_m mods[m] * W_pred[(j*4+k)*4 + m]
    float coefT[4][4];
#pragma unroll
    for (int j = 0; j < 4; ++j)
#pragma unroll
        for (int k = 0; k < 4; ++k) {
            float s = 0.f;
#pragma unroll
            for (int m = 0; m < 4; ++m) s += mods[m] * W_pred[(j * 4 + k) * 4 + m];
            coefT[k][j] = s;
        }
    float ccoef[4];
#pragma unroll
    for (int j = 0; j < 4; ++j) {
        float s = 1.0f;
#pragma unroll
        for (int m = 0; m < 4; ++m) s += modsc[m] * W_corr[j * 4 + m];
        ccoef[j] = s;
    }

    // ---- pass 2: predictions + correction, 4 output rows ----
#pragma unroll
    for (int c = 0; c < 2; ++c) {
        const int h = c * 1024 + tid * 4;
        float4 xk4[4];
        xk4[0] = *reinterpret_cast<const float4*>(s_x0 + h);
        xk4[1] = *reinterpret_cast<const float4*>(hs + plane + row + h);
        xk4[2] = *reinterpret_cast<const float4*>(hs + 2 * plane + row + h);
        xk4[3] = *reinterpret_cast<const float4*>(hs + 3 * plane + row + h);
        const float4 xc4 = *reinterpret_cast<const float4*>(s_xc + h);
        float4 o4[4];
#pragma unroll
        for (int e = 0; e < 4; ++e) {
            float xk[4];
#pragma unroll
            for (int k = 0; k < 4; ++k) xk[k] = (&xk4[k].x)[e];
            const float xce = (&xc4.x)[e];
            float pred[4];
#pragma unroll
            for (int j = 0; j < 4; ++j) {
                float s = xk[j]; // "+ stacked" residual
#pragma unroll
                for (int k = 0; k < 4; ++k) s += xk[k] * coefT[k][j];
                pred[j] = s;
            }
            const float innov = xce - pred[0];
#pragma unroll
            for (int j = 0; j < 4; ++j)
                (&o4[j].x)[e] = pred[j] + innov * ccoef[j];
        }
#pragma unroll
        for (int j = 0; j < 4; ++j)
            *reinterpret_cast<float4*>(out + j * plane + row + h) = o4[j];
    }
}

extern "C" void kernel_launch(void* const* d_in, const int* in_sizes, int n_in,
                              void* d_out, int out_size, void* d_ws, size_t ws_size,
                              hipStream_t stream) {
    const float* hs       = (const float*)d_in[0];
    const float* act      = (const float*)d_in[1];
    const float* w_norm   = (const float*)d_in[2];
    const float* W_router = (const float*)d_in[3];
    const float* W_pred   = (const float*)d_in[4];
    const float* W_corr   = (const float*)d_in[5];
    float* out = (float*)d_out;
    const long long T = (long long)in_sizes[0] / (4LL * H); // B*S
    altup_fused<<<dim3((unsigned)T), dim3(256), 0, stream>>>(
        hs, act, w_norm, W_router, W_pred, W_corr, out, T);
}

// Round 2
// 121.353 us; speedup vs baseline: 1.0593x; 1.0593x over previous
//
#include <hip/hip_runtime.h>

// Gemma3n AltUp fused: predict + correct in one kernel.
// Shapes: hidden_states [4, T, H], activated [T, H], w_norm [H],
//         W_router [4, H], W_pred [16, 4], W_corr [4, 4], out [4, T, H]
// T = B*S = 8192, H = 2048. All fp32. Memory-bound (~604 MB HBM traffic).
//
// R2: one thread per float4 chunk (512 thr/block), ALL streaming loads issued
// before the block reduction so HBM latency hides under the barrier wait.
// No LDS row staging (only 320 B for cross-wave reduce).

constexpr int H = 2048;
constexpr float EPS = 1e-6f;

__global__ __launch_bounds__(512) void altup_fused(
    const float* __restrict__ hs,       // [4, T, H]
    const float* __restrict__ act,      // [T, H]
    const float* __restrict__ w_norm,   // [H]
    const float* __restrict__ W_router, // [4, H]
    const float* __restrict__ W_pred,   // [16, 4]
    const float* __restrict__ W_corr,   // [4, 4]
    float* __restrict__ out,            // [4, T, H]
    long long T)
{
    const long long t = blockIdx.x;
    const int tid = threadIdx.x;
    const long long row = t * (long long)H;
    const long long plane = T * (long long)H;
    const int h = tid * 4;

    __shared__ float s_red[8][10];

    // ---- issue ALL streaming loads up-front (registers, not LDS) ----
    const float4 x0 = *reinterpret_cast<const float4*>(hs + row + h);
    const float4 x1 = *reinterpret_cast<const float4*>(hs + plane + row + h);
    const float4 x2 = *reinterpret_cast<const float4*>(hs + 2 * plane + row + h);
    const float4 x3 = *reinterpret_cast<const float4*>(hs + 3 * plane + row + h);
    const float4 xc = *reinterpret_cast<const float4*>(act + row + h);
    const float4 wn = *reinterpret_cast<const float4*>(w_norm + h);

    // ---- partials ----
    // p[0]=ssq(x0), p[1..4]=dot(x0*w, Wr[i]), p[5]=ssq(xc), p[6..9]=dot(xc*w, Wr[i])
    float p[10];
    {
        const float* a = &x0.x;
        const float* c = &xc.x;
        const float* w = &wn.x;
        float s0 = 0.f, s5 = 0.f;
#pragma unroll
        for (int e = 0; e < 4; ++e) { s0 += a[e] * a[e]; s5 += c[e] * c[e]; }
        p[0] = s0; p[5] = s5;
#pragma unroll
        for (int i = 0; i < 4; ++i) {
            const float4 wr4 = *reinterpret_cast<const float4*>(W_router + i * H + h);
            const float* r = &wr4.x;
            float da = 0.f, dc = 0.f;
#pragma unroll
            for (int e = 0; e < 4; ++e) {
                const float wre = w[e] * r[e];
                da += a[e] * wre;
                dc += c[e] * wre;
            }
            p[1 + i] = da; p[6 + i] = dc;
        }
    }

    // ---- wave-64 butterfly + cross-wave reduce ----
#pragma unroll
    for (int m = 1; m < 64; m <<= 1) {
#pragma unroll
        for (int i = 0; i < 10; ++i) p[i] += __shfl_xor(p[i], m, 64);
    }
    const int wave = tid >> 6;
    if ((tid & 63) == 0) {
#pragma unroll
        for (int i = 0; i < 10; ++i) s_red[wave][i] = p[i];
    }
    __syncthreads();

    float tot[10];
#pragma unroll
    for (int i = 0; i < 10; ++i) {
        float s = 0.f;
#pragma unroll
        for (int wv = 0; wv < 8; ++wv) s += s_red[wv][i];
        tot[i] = s;
    }

    // ---- tiny coefficient math (redundant per thread; scalar broadcasts) ----
    const float ris = 1.0f / (float)H;                    // ROUTER_INPUT_SCALE
    const float inv_a = rsqrtf(tot[0] * ris + EPS) * ris; // rsqrt(var+eps)/H
    const float inv_c = rsqrtf(tot[5] * ris + EPS) * ris;
    float mods[4], modsc[4];
#pragma unroll
    for (int i = 0; i < 4; ++i) {
        mods[i]  = tanhf(tot[1 + i] * inv_a);
        modsc[i] = tanhf(tot[6 + i] * inv_c);
    }
    // coefs = mods @ W_pred.T -> reshape [4][4] -> swapaxes:
    // coefT[k][j] = sum_m mods[m] * W_pred[(j*4+k)*4 + m]
    float coefT[4][4];
#pragma unroll
    for (int j = 0; j < 4; ++j)
#pragma unroll
        for (int k = 0; k < 4; ++k) {
            float s = 0.f;
#pragma unroll
            for (int m = 0; m < 4; ++m) s += mods[m] * W_pred[(j * 4 + k) * 4 + m];
            coefT[k][j] = s;
        }
    float ccoef[4];
#pragma unroll
    for (int j = 0; j < 4; ++j) {
        float s = 1.0f;
#pragma unroll
        for (int m = 0; m < 4; ++m) s += modsc[m] * W_corr[j * 4 + m];
        ccoef[j] = s;
    }

    // ---- predictions + correction from registers ----
    const float* xk0 = &x0.x;
    const float* xk1 = &x1.x;
    const float* xk2 = &x2.x;
    const float* xk3 = &x3.x;
    const float* xce = &xc.x;
    float4 o4[4];
#pragma unroll
    for (int e = 0; e < 4; ++e) {
        const float xk[4] = { xk0[e], xk1[e], xk2[e], xk3[e] };
        float pred[4];
#pragma unroll
        for (int j = 0; j < 4; ++j) {
            float s = xk[j]; // "+ stacked" residual
#pragma unroll
            for (int k = 0; k < 4; ++k) s += xk[k] * coefT[k][j];
            pred[j] = s;
        }
        const float innov = xce[e] - pred[0];
#pragma unroll
        for (int j = 0; j < 4; ++j)
            (&o4[j].x)[e] = pred[j] + innov * ccoef[j];
    }
#pragma unroll
    for (int j = 0; j < 4; ++j)
        *reinterpret_cast<float4*>(out + j * plane + row + h) = o4[j];
}

extern "C" void kernel_launch(void* const* d_in, const int* in_sizes, int n_in,
                              void* d_out, int out_size, void* d_ws, size_t ws_size,
                              hipStream_t stream) {
    const float* hs       = (const float*)d_in[0];
    const float* act      = (const float*)d_in[1];
    const float* w_norm   = (const float*)d_in[2];
    const float* W_router = (const float*)d_in[3];
    const float* W_pred   = (const float*)d_in[4];
    const float* W_corr   = (const float*)d_in[5];
    float* out = (float*)d_out;
    const long long T = (long long)in_sizes[0] / (4LL * H); // B*S
    altup_fused<<<dim3((unsigned)T), dim3(512), 0, stream>>>(
        hs, act, w_norm, W_router, W_pred, W_corr, out, T);
}